// Round 10
// baseline (314.865 us; speedup 1.0000x reference)
//
#include <hip/hip_runtime.h>

#define BB 16
#define CC 256
#define NN 1024

typedef _Float16 f16;
typedef __attribute__((ext_vector_type(8))) _Float16 half8;   // MFMA A/B frag (4 VGPRs)
typedef __attribute__((ext_vector_type(4))) float f32x4;      // MFMA C/D frag

__device__ __forceinline__ half8 ldg8(const f16* p) {
  return *reinterpret_cast<const half8*>(p);
}

// ---------------- weight pack: W fp32 [ci][co] -> frag-packed f16 wp[(ct*8+kc)*512 + lane*8] ----
// frag (ct,kc): lane(row16,quad) holds W^T[ct*16+row16][kc*32+quad*8 .. +7] = W[kc*32+quad*8+j][ct*16+row16]
struct WP5 {
  const float* s[5];
  f16* d[5];
};

__global__ void __launch_bounds__(256) k_packW(WP5 p) {
  __shared__ float ws[256][17];
  int m = blockIdx.y, ct = blockIdx.x;
  const float* W = p.s[m];
  f16* wp = p.d[m];
  int tid = threadIdx.x;
  int col = tid & 15, cig = tid >> 4;
#pragma unroll
  for (int pg = 0; pg < 16; ++pg) {
    int ci = pg * 16 + cig;
    ws[ci][col] = W[(size_t)ci * 256 + ct * 16 + col];
  }
  __syncthreads();
  int lane = tid & 63, wave = tid >> 6;
  int row16 = lane & 15, quad = lane >> 4;
#pragma unroll
  for (int kk = 0; kk < 2; ++kk) {
    int kc = wave * 2 + kk;
    half8 o;
#pragma unroll
    for (int j = 0; j < 8; ++j) o[j] = (f16)ws[kc * 32 + quad * 8 + j][row16];
    *reinterpret_cast<half8*>(wp + ((size_t)ct * 8 + kc) * 512 + lane * 8) = o;
  }
}

// ---------------- QKV: x fp32 [bg][c][n] -> frag-packed q,k,vT ----------------
// q/k: frag (ntile = by*2+g, kc): lane holds q[nt*16+row16][kc*32+quad*8..+7]
// v:   frag (ib = by, ct):       lane holds vT[ct*16+row16][ib*32+quad*8..+7]
// grid (nb, N/32, 3) — batch on x for XCD locality. block 256 = 4 waves (g=wave>>1 rows, h=wave&1 cols)
struct QkvSmem {
  union {
    struct { f16 hi[32][264]; f16 lo[32][264]; } ts;  // x-tile transposed, hi/lo split
    f16 ex[2][16][264];                               // q/k per-rowgroup exchange
    f16 exv[256][40];                                 // v exchange [co][n_local]
  };
};

__global__ void __launch_bounds__(256) k_qkv(const float* __restrict__ x,
    const f16* __restrict__ wqp, const f16* __restrict__ wkp, const f16* __restrict__ wvp,
    const float* __restrict__ bq, const float* __restrict__ bk, const float* __restrict__ bv,
    f16* __restrict__ qp, f16* __restrict__ kp, f16* __restrict__ vp, int b_base) {
  __shared__ QkvSmem sm;
  int z = blockIdx.z;
  const f16* WT     = (z == 0) ? wqp : (z == 1) ? wkp : wvp;
  const float* bias = (z == 0) ? bq  : (z == 1) ? bk  : bv;
  int bl = blockIdx.x, bg = b_base + bl, n0 = blockIdx.y * 32;
  int tid = threadIdx.x, wave = tid >> 6, lane = tid & 63;
  int row16 = lane & 15, quad = lane >> 4;
  int g = wave >> 1, h = wave & 1;

  // stage x[bg, :, n0:n0+32] transposed + hi/lo split
#pragma unroll
  for (int e = tid; e < 2048; e += 256) {
    int c = e >> 3, n4 = (e & 7) << 2;
    float4 u = *reinterpret_cast<const float4*>(x + (size_t)(bg * CC + c) * NN + n0 + n4);
    float uv[4] = {u.x, u.y, u.z, u.w};
#pragma unroll
    for (int i = 0; i < 4; ++i) {
      f16 hh = (f16)uv[i];
      sm.ts.hi[n4 + i][c] = hh;
      sm.ts.lo[n4 + i][c] = (f16)(uv[i] - (float)hh);
    }
  }
  __syncthreads();

  half8 ah[8], al[8];
#pragma unroll
  for (int kc = 0; kc < 8; ++kc) {
    ah[kc] = *reinterpret_cast<const half8*>(&sm.ts.hi[g * 16 + row16][kc * 32 + quad * 8]);
    al[kc] = *reinterpret_cast<const half8*>(&sm.ts.lo[g * 16 + row16][kc * 32 + quad * 8]);
  }
  __syncthreads();  // ts dead; memory reused as ex/exv below

  if (z < 2) {
    // q or k: wave (g,h) computes col-half h of its 16-row group -> LDS -> packed frag stores
    f16* outp = z ? kp : qp;
#pragma unroll
    for (int ct8 = 0; ct8 < 8; ++ct8) {
      int ct = h * 8 + ct8;
      f32x4 acc = {0.f, 0.f, 0.f, 0.f};
      const f16* bh = WT + ((size_t)ct * 8) * 512 + lane * 8;
#pragma unroll
      for (int kc = 0; kc < 8; ++kc) {
        half8 b = ldg8(bh + kc * 512);
        acc = __builtin_amdgcn_mfma_f32_16x16x32_f16(ah[kc], b, acc, 0, 0, 0);
        acc = __builtin_amdgcn_mfma_f32_16x16x32_f16(al[kc], b, acc, 0, 0, 0);
      }
      int co = ct * 16 + row16;
      float bb = bias[co];
#pragma unroll
      for (int r = 0; r < 4; ++r)
        sm.ex[g][quad * 4 + r][co] = (f16)(acc[r] + bb);
    }
    // same-wave write->read (rows swap within wave, cols stay in own half): no barrier
    const f16* exr = &sm.ex[g][row16][0];
    size_t fb = ((size_t)bl * 64 + (n0 >> 4) + g) * 8;
#pragma unroll
    for (int k = 0; k < 4; ++k) {
      int kc = h * 4 + k;
      half8 hv = *reinterpret_cast<const half8*>(exr + kc * 32 + quad * 8);
      *reinterpret_cast<half8*>(outp + (fb + kc) * 512 + lane * 8) = hv;
    }
  } else {
    // v: compute -> exv[co][n_local] -> barrier -> packed frag stores (frag = (ib=by, ct))
#pragma unroll
    for (int ct8 = 0; ct8 < 8; ++ct8) {
      int ct = h * 8 + ct8;
      f32x4 acc = {0.f, 0.f, 0.f, 0.f};
      const f16* bh = WT + ((size_t)ct * 8) * 512 + lane * 8;
#pragma unroll
      for (int kc = 0; kc < 8; ++kc) {
        half8 b = ldg8(bh + kc * 512);
        acc = __builtin_amdgcn_mfma_f32_16x16x32_f16(ah[kc], b, acc, 0, 0, 0);
        acc = __builtin_amdgcn_mfma_f32_16x16x32_f16(al[kc], b, acc, 0, 0, 0);
      }
      int co = ct * 16 + row16;
      float bb = bias[co];
#pragma unroll
      for (int r = 0; r < 4; ++r)
        sm.exv[co][g * 16 + quad * 4 + r] = (f16)(acc[r] + bb);
    }
    __syncthreads();  // cross-wave exchange
    size_t vb = ((size_t)bl * 32 + blockIdx.y) * 16;
#pragma unroll
    for (int f = 0; f < 4; ++f) {
      int ct = wave * 4 + f;
      half8 o = *reinterpret_cast<const half8*>(&sm.exv[ct * 16 + row16][quad * 8]);
      *reinterpret_cast<half8*>(vp + (vb + ct) * 512 + lane * 8) = o;
    }
  }
}

// ---------------- fused flash attention (swapped roles, split-i) + MLP(SiLU) + LayerNorm ----------
// grid (nb, N/32). block 256 = 4 waves: jg = wave>>1 (16 j-rows), ic = wave&1 (i-chunk of 512).
// All A/B frags are packed 1 KB loads. One barrier (softmax merge); phase B on ic==0 waves.
struct AttnSmem {
  f16 P[4][16][40];       // per-wave P (C->A layout round-trip)
  f16 Om[2][16][272];     // merge buffer (ic==1 partial O)
  float ml[2][2][16];     // per j-group: m,l per row from ic==1
  f16 ex[2][16][264];     // per j-group exchange (att, h) for phase B
};

__global__ void __launch_bounds__(256, 4) k_attn_mlp(
    const f16* __restrict__ qp, const f16* __restrict__ kp, const f16* __restrict__ vp,
    const f16* __restrict__ w1p, const float* __restrict__ b1,
    const f16* __restrict__ w2p, const float* __restrict__ b2,
    const float* __restrict__ gamma, const float* __restrict__ beta,
    float* __restrict__ out, int b_base) {
  __shared__ AttnSmem sm;
  int bl = blockIdx.x, bg = b_base + bl;
  int j0 = blockIdx.y * 32;
  int tid = threadIdx.x, wave = tid >> 6, lane = tid & 63;
  int row16 = lane & 15, quad = lane >> 4;
  int jg = wave >> 1, ic = wave & 1;
  int jw = j0 + jg * 16;

  // A-frags: k rows j (packed)
  const f16* kbase = kp + (size_t)bl * NN * CC;
  int jt = (j0 >> 4) + jg;
  half8 kf[8];
#pragma unroll
  for (int kc = 0; kc < 8; ++kc)
    kf[kc] = ldg8(kbase + ((size_t)jt * 8 + kc) * 512 + lane * 8);

  const f16* qbase = qp + (size_t)bl * NN * CC;
  const f16* vbase = vp + (size_t)bl * CC * NN;

  f32x4 O[16];
#pragma unroll
  for (int ct = 0; ct < 16; ++ct) O[ct] = {0.f, 0.f, 0.f, 0.f};
  float m_run[4], l_run[4];
#pragma unroll
  for (int r = 0; r < 4; ++r) { m_run[r] = -1e30f; l_run[r] = 0.f; }

  for (int it = 0; it < 16; ++it) {
    int ft = ic * 32 + it * 2;   // q i-tile (16 rows each)
    // scores S[16 j][32 i]: packed q frags (1 KB coalesced)
    f32x4 s0 = {0.f, 0.f, 0.f, 0.f}, s1 = {0.f, 0.f, 0.f, 0.f};
#pragma unroll
    for (int kc = 0; kc < 8; ++kc) {
      half8 b0  = ldg8(qbase + ((size_t)ft * 8 + kc) * 512 + lane * 8);
      half8 b1v = ldg8(qbase + ((size_t)(ft + 1) * 8 + kc) * 512 + lane * 8);
      s0 = __builtin_amdgcn_mfma_f32_16x16x32_f16(kf[kc], b0, s0, 0, 0, 0);
      s1 = __builtin_amdgcn_mfma_f32_16x16x32_f16(kf[kc], b1v, s1, 0, 0, 0);
    }

    // online softmax per j-row
    float alpha[4];
#pragma unroll
    for (int r = 0; r < 4; ++r) {
      float mx = fmaxf(s0[r], s1[r]);
#pragma unroll
      for (int off = 1; off < 16; off <<= 1) mx = fmaxf(mx, __shfl_xor(mx, off, 64));
      float mnew = fmaxf(m_run[r], mx);
      alpha[r] = __expf(m_run[r] - mnew);
      m_run[r] = mnew;
      float p0 = __expf(s0[r] - mnew);
      float p1 = __expf(s1[r] - mnew);
      float sm2 = p0 + p1;
#pragma unroll
      for (int off = 1; off < 16; off <<= 1) sm2 += __shfl_xor(sm2, off, 64);
      l_run[r] = l_run[r] * alpha[r] + sm2;
      sm.P[wave][quad * 4 + r][row16]      = (f16)p0;
      sm.P[wave][quad * 4 + r][16 + row16] = (f16)p1;
    }
#pragma unroll
    for (int ct = 0; ct < 16; ++ct)
#pragma unroll
      for (int r = 0; r < 4; ++r) O[ct][r] *= alpha[r];

    // PV: packed vT frags (ib = ic*16+it)
    half8 pf = *reinterpret_cast<const half8*>(&sm.P[wave][row16][quad * 8]);
    size_t vfb = ((size_t)(ic * 16 + it) * 16) * 512;
#pragma unroll
    for (int ct = 0; ct < 16; ++ct) {
      half8 vf = ldg8(vbase + vfb + (size_t)ct * 512 + lane * 8);
      O[ct] = __builtin_amdgcn_mfma_f32_16x16x32_f16(pf, vf, O[ct], 0, 0, 0);
    }
  }

  // ---- merge the two i-chunks (online-softmax combine) ----
  if (ic == 1) {
#pragma unroll
    for (int ct = 0; ct < 16; ++ct)
#pragma unroll
      for (int r = 0; r < 4; ++r)
        sm.Om[jg][quad * 4 + r][ct * 16 + row16] = (f16)O[ct][r];
    if (row16 == 0) {
#pragma unroll
      for (int r = 0; r < 4; ++r) {
        sm.ml[jg][0][quad * 4 + r] = m_run[r];
        sm.ml[jg][1][quad * 4 + r] = l_run[r];
      }
    }
  }
  __syncthreads();
  if (ic == 1) return;

  float a0[4], a1[4], inv[4];
#pragma unroll
  for (int r = 0; r < 4; ++r) {
    float m1 = sm.ml[jg][0][quad * 4 + r];
    float l1 = sm.ml[jg][1][quad * 4 + r];
    float M = fmaxf(m_run[r], m1);
    a0[r] = __expf(m_run[r] - M);
    a1[r] = __expf(m1 - M);
    inv[r] = 1.f / (l_run[r] * a0[r] + l1 * a1[r]);
  }

  // ---- phase B: MLP + LN on this j-group's 16x256 att tile ----
#pragma unroll
  for (int ct = 0; ct < 16; ++ct)
#pragma unroll
    for (int r = 0; r < 4; ++r) {
      float o1 = (float)sm.Om[jg][quad * 4 + r][ct * 16 + row16];
      sm.ex[jg][quad * 4 + r][ct * 16 + row16] =
          (f16)((O[ct][r] * a0[r] + o1 * a1[r]) * inv[r]);
    }

  half8 af[8];
#pragma unroll
  for (int kc = 0; kc < 8; ++kc)
    af[kc] = *reinterpret_cast<const half8*>(&sm.ex[jg][row16][kc * 32 + quad * 8]);

  // GEMM1: h = silu(att @ w1 + b1) -> ex (own j-group rows); packed weight frags
#pragma unroll
  for (int ct = 0; ct < 16; ++ct) {
    f32x4 acc = {0.f, 0.f, 0.f, 0.f};
    const f16* brow = w1p + ((size_t)ct * 8) * 512 + lane * 8;
#pragma unroll
    for (int kc = 0; kc < 8; ++kc)
      acc = __builtin_amdgcn_mfma_f32_16x16x32_f16(af[kc], ldg8(brow + kc * 512), acc, 0, 0, 0);
    int co = ct * 16 + row16;
    float bb = b1[co];
#pragma unroll
    for (int r = 0; r < 4; ++r) {
      float xg = acc[r] + bb;
      float hh = xg / (1.f + __expf(-xg));  // SiLU
      sm.ex[jg][quad * 4 + r][co] = (f16)hh;
    }
  }

  half8 hf[8];
#pragma unroll
  for (int kc = 0; kc < 8; ++kc)
    hf[kc] = *reinterpret_cast<const half8*>(&sm.ex[jg][row16][kc * 32 + quad * 8]);

  f32x4 acc2[16];
#pragma unroll
  for (int ct = 0; ct < 16; ++ct) {
    f32x4 acc = {0.f, 0.f, 0.f, 0.f};
    const f16* brow = w2p + ((size_t)ct * 8) * 512 + lane * 8;
#pragma unroll
    for (int kc = 0; kc < 8; ++kc)
      acc = __builtin_amdgcn_mfma_f32_16x16x32_f16(hf[kc], ldg8(brow + kc * 512), acc, 0, 0, 0);
    float bb = b2[ct * 16 + row16];
#pragma unroll
    for (int r = 0; r < 4; ++r) acc[r] += bb;
    acc2[ct] = acc;
  }

  // LayerNorm over C (per-row stats via 16-lane butterfly)
  float sum[4] = {0.f, 0.f, 0.f, 0.f}, ssq[4] = {0.f, 0.f, 0.f, 0.f};
#pragma unroll
  for (int ct = 0; ct < 16; ++ct)
#pragma unroll
    for (int r = 0; r < 4; ++r) { float xv = acc2[ct][r]; sum[r] += xv; ssq[r] += xv * xv; }
  float mean[4], rstd[4];
#pragma unroll
  for (int r = 0; r < 4; ++r) {
#pragma unroll
    for (int off = 1; off < 16; off <<= 1) {
      sum[r] += __shfl_xor(sum[r], off, 64);
      ssq[r] += __shfl_xor(ssq[r], off, 64);
    }
    mean[r] = sum[r] * (1.f / 256.f);
    float var = ssq[r] * (1.f / 256.f) - mean[r] * mean[r];
    rstd[r] = rsqrtf(var + 1e-5f);
  }

  // direct coalesced stores: out[bg][col][jw + quad*4 .. +3] = float4
#pragma unroll
  for (int ct = 0; ct < 16; ++ct) {
    int col = ct * 16 + row16;
    float g = gamma[col], be = beta[col];
    f32x4 v;
#pragma unroll
    for (int r = 0; r < 4; ++r) v[r] = (acc2[ct][r] - mean[r]) * rstd[r] * g + be;
    *reinterpret_cast<f32x4*>(out + (size_t)(bg * CC + col) * NN + jw + quad * 4) = v;
  }
}

extern "C" void kernel_launch(void* const* d_in, const int* in_sizes, int n_in,
                              void* d_out, int out_size, void* d_ws, size_t ws_size,
                              hipStream_t stream) {
  (void)in_sizes; (void)n_in; (void)out_size;
  const float* x     = (const float*)d_in[0];
  const float* wq    = (const float*)d_in[1];
  const float* bq    = (const float*)d_in[2];
  const float* wk    = (const float*)d_in[3];
  const float* bk    = (const float*)d_in[4];
  const float* wv    = (const float*)d_in[5];
  const float* bv    = (const float*)d_in[6];
  const float* w1    = (const float*)d_in[7];
  const float* b1    = (const float*)d_in[8];
  const float* w2    = (const float*)d_in[9];
  const float* b2    = (const float*)d_in[10];
  const float* gamma = (const float*)d_in[11];
  const float* beta  = (const float*)d_in[12];
  float* out = (float*)d_out;

  // workspace (all f16): [5 packed weights][q][k][vT] chunked over batches
  const size_t WE = 65536;
  const size_t SB = (size_t)NN * CC;
  f16* base = (f16*)d_ws;
  f16* wqp = base + 0 * WE;
  f16* wkp = base + 1 * WE;
  f16* wvp = base + 2 * WE;
  f16* w1p = base + 3 * WE;
  f16* w2p = base + 4 * WE;

  size_t wbytes = 5 * WE * sizeof(f16);
  size_t perb   = 3 * SB * sizeof(f16);
  int nb = (ws_size > wbytes) ? (int)((ws_size - wbytes) / perb) : 1;
  if (nb < 1) nb = 1;
  if (nb > BB) nb = BB;

  f16* qb  = base + 5 * WE;
  f16* kb  = qb + (size_t)nb * SB;
  f16* vTb = kb + (size_t)nb * SB;

  WP5 p;
  p.s[0] = wq; p.s[1] = wk; p.s[2] = wv; p.s[3] = w1; p.s[4] = w2;
  p.d[0] = wqp; p.d[1] = wkp; p.d[2] = wvp; p.d[3] = w1p; p.d[4] = w2p;
  k_packW<<<dim3(16, 5), 256, 0, stream>>>(p);

  for (int b0 = 0; b0 < BB; b0 += nb) {
    int cb = (b0 + nb <= BB) ? nb : (BB - b0);
    // batch on gridDim.x: with cb a multiple of 8, blocks of one batch share an XCD
    k_qkv<<<dim3(cb, 32, 3), 256, 0, stream>>>(x, wqp, wkp, wvp, bq, bk, bv, qb, kb, vTb, b0);
    k_attn_mlp<<<dim3(cb, 32), 256, 0, stream>>>(qb, kb, vTb, w1p, b1, w2p, b2,
                                                 gamma, beta, out, b0);
  }
}

// Round 11
// 282.988 us; speedup vs baseline: 1.1126x; 1.1126x over previous
//
#include <hip/hip_runtime.h>

#define BB 16
#define CC 256
#define NN 1024

typedef _Float16 f16;
typedef __attribute__((ext_vector_type(8))) _Float16 half8;   // MFMA A/B frag (4 VGPRs)
typedef __attribute__((ext_vector_type(4))) float f32x4;      // MFMA C/D frag

__device__ __forceinline__ half8 ldg8(const f16* p) {
  return *reinterpret_cast<const half8*>(p);
}

// ---------------- weight pack: W fp32 [ci][co] -> frag-packed f16 wp[(ct*8+kc)*512 + lane*8] ----
struct WP5 {
  const float* s[5];
  f16* d[5];
};

__global__ void __launch_bounds__(256) k_packW(WP5 p) {
  __shared__ float ws[256][17];
  int m = blockIdx.y, ct = blockIdx.x;
  const float* W = p.s[m];
  f16* wp = p.d[m];
  int tid = threadIdx.x;
  int col = tid & 15, cig = tid >> 4;
#pragma unroll
  for (int pg = 0; pg < 16; ++pg) {
    int ci = pg * 16 + cig;
    ws[ci][col] = W[(size_t)ci * 256 + ct * 16 + col];
  }
  __syncthreads();
  int lane = tid & 63, wave = tid >> 6;
  int row16 = lane & 15, quad = lane >> 4;
#pragma unroll
  for (int kk = 0; kk < 2; ++kk) {
    int kc = wave * 2 + kk;
    half8 o;
#pragma unroll
    for (int j = 0; j < 8; ++j) o[j] = (f16)ws[kc * 32 + quad * 8 + j][row16];
    *reinterpret_cast<half8*>(wp + ((size_t)ct * 8 + kc) * 512 + lane * 8) = o;
  }
}

// ---------------- QKV: x fp32 [bg][c][n] -> frag-packed q,k,vT (same as R10) ----------------
struct QkvSmem {
  union {
    struct { f16 hi[32][264]; f16 lo[32][264]; } ts;
    f16 ex[2][16][264];
    f16 exv[256][40];
  };
};

__global__ void __launch_bounds__(256) k_qkv(const float* __restrict__ x,
    const f16* __restrict__ wqp, const f16* __restrict__ wkp, const f16* __restrict__ wvp,
    const float* __restrict__ bq, const float* __restrict__ bk, const float* __restrict__ bv,
    f16* __restrict__ qp, f16* __restrict__ kp, f16* __restrict__ vp, int b_base) {
  __shared__ QkvSmem sm;
  int z = blockIdx.z;
  const f16* WT     = (z == 0) ? wqp : (z == 1) ? wkp : wvp;
  const float* bias = (z == 0) ? bq  : (z == 1) ? bk  : bv;
  int bl = blockIdx.x, bg = b_base + bl, n0 = blockIdx.y * 32;
  int tid = threadIdx.x, wave = tid >> 6, lane = tid & 63;
  int row16 = lane & 15, quad = lane >> 4;
  int g = wave >> 1, h = wave & 1;

#pragma unroll
  for (int e = tid; e < 2048; e += 256) {
    int c = e >> 3, n4 = (e & 7) << 2;
    float4 u = *reinterpret_cast<const float4*>(x + (size_t)(bg * CC + c) * NN + n0 + n4);
    float uv[4] = {u.x, u.y, u.z, u.w};
#pragma unroll
    for (int i = 0; i < 4; ++i) {
      f16 hh = (f16)uv[i];
      sm.ts.hi[n4 + i][c] = hh;
      sm.ts.lo[n4 + i][c] = (f16)(uv[i] - (float)hh);
    }
  }
  __syncthreads();

  half8 ah[8], al[8];
#pragma unroll
  for (int kc = 0; kc < 8; ++kc) {
    ah[kc] = *reinterpret_cast<const half8*>(&sm.ts.hi[g * 16 + row16][kc * 32 + quad * 8]);
    al[kc] = *reinterpret_cast<const half8*>(&sm.ts.lo[g * 16 + row16][kc * 32 + quad * 8]);
  }
  __syncthreads();

  if (z < 2) {
    f16* outp = z ? kp : qp;
#pragma unroll
    for (int ct8 = 0; ct8 < 8; ++ct8) {
      int ct = h * 8 + ct8;
      f32x4 acc = {0.f, 0.f, 0.f, 0.f};
      const f16* bh = WT + ((size_t)ct * 8) * 512 + lane * 8;
#pragma unroll
      for (int kc = 0; kc < 8; ++kc) {
        half8 b = ldg8(bh + kc * 512);
        acc = __builtin_amdgcn_mfma_f32_16x16x32_f16(ah[kc], b, acc, 0, 0, 0);
        acc = __builtin_amdgcn_mfma_f32_16x16x32_f16(al[kc], b, acc, 0, 0, 0);
      }
      int co = ct * 16 + row16;
      float bb = bias[co];
#pragma unroll
      for (int r = 0; r < 4; ++r)
        sm.ex[g][quad * 4 + r][co] = (f16)(acc[r] + bb);
    }
    const f16* exr = &sm.ex[g][row16][0];
    size_t fb = ((size_t)bl * 64 + (n0 >> 4) + g) * 8;
#pragma unroll
    for (int k = 0; k < 4; ++k) {
      int kc = h * 4 + k;
      half8 hv = *reinterpret_cast<const half8*>(exr + kc * 32 + quad * 8);
      *reinterpret_cast<half8*>(outp + (fb + kc) * 512 + lane * 8) = hv;
    }
  } else {
#pragma unroll
    for (int ct8 = 0; ct8 < 8; ++ct8) {
      int ct = h * 8 + ct8;
      f32x4 acc = {0.f, 0.f, 0.f, 0.f};
      const f16* bh = WT + ((size_t)ct * 8) * 512 + lane * 8;
#pragma unroll
      for (int kc = 0; kc < 8; ++kc) {
        half8 b = ldg8(bh + kc * 512);
        acc = __builtin_amdgcn_mfma_f32_16x16x32_f16(ah[kc], b, acc, 0, 0, 0);
        acc = __builtin_amdgcn_mfma_f32_16x16x32_f16(al[kc], b, acc, 0, 0, 0);
      }
      int co = ct * 16 + row16;
      float bb = bias[co];
#pragma unroll
      for (int r = 0; r < 4; ++r)
        sm.exv[co][g * 16 + quad * 4 + r] = (f16)(acc[r] + bb);
    }
    __syncthreads();
    size_t vb = ((size_t)bl * 32 + blockIdx.y) * 16;
#pragma unroll
    for (int f = 0; f < 4; ++f) {
      int ct = wave * 4 + f;
      half8 o = *reinterpret_cast<const half8*>(&sm.exv[ct * 16 + row16][quad * 8]);
      *reinterpret_cast<half8*>(vp + (vb + ct) * 512 + lane * 8) = o;
    }
  }
}

// ---------------- fused flash attention + MLP(SiLU) + LayerNorm — 128-i iterations ----------------
// grid (nb, 16). block 256 = 4 independent waves, each owns 16 j-rows, sweeps all 1024 i
// in 8 iterations of 128 i (8 score-frags per iter; softmax amortized 4x; lazy l-reduce).
// ZERO barriers: P and ex are per-wave and live in disjoint LDS.
struct AttnSmem {
  f16 P[4][4][16][40];   // per-wave, per-32i-chunk P (C->A layout round-trip)  20.5 KB
  f16 ex[4][16][264];    // per-wave exchange (att, h) for phase B              33.8 KB
};

__global__ void __launch_bounds__(256) k_attn_mlp(
    const f16* __restrict__ qp, const f16* __restrict__ kp, const f16* __restrict__ vp,
    const f16* __restrict__ w1p, const float* __restrict__ b1,
    const f16* __restrict__ w2p, const float* __restrict__ b2,
    const float* __restrict__ gamma, const float* __restrict__ beta,
    float* __restrict__ out, int b_base) {
  __shared__ AttnSmem sm;
  int bl = blockIdx.x, bg = b_base + bl;
  int j0 = blockIdx.y * 64;
  int tid = threadIdx.x, wave = tid >> 6, lane = tid & 63;
  int row16 = lane & 15, quad = lane >> 4;
  int jw = j0 + wave * 16;

  // A-frags: k rows j (packed)
  const f16* kbase = kp + (size_t)bl * NN * CC;
  int jt = (j0 >> 4) + wave;
  half8 kf[8];
#pragma unroll
  for (int kc = 0; kc < 8; ++kc)
    kf[kc] = ldg8(kbase + ((size_t)jt * 8 + kc) * 512 + lane * 8);

  const f16* qbase = qp + (size_t)bl * NN * CC;
  const f16* vbase = vp + (size_t)bl * CC * NN;

  f32x4 O[16];
#pragma unroll
  for (int ct = 0; ct < 16; ++ct) O[ct] = {0.f, 0.f, 0.f, 0.f};
  float m_run[4], l_lane[4];
#pragma unroll
  for (int r = 0; r < 4; ++r) { m_run[r] = -1e30f; l_lane[r] = 0.f; }

  for (int it = 0; it < 8; ++it) {
    // scores S[16 j][128 i]: 8 frags, 8 parallel MFMA chains
    f32x4 s[8];
#pragma unroll
    for (int f = 0; f < 8; ++f) s[f] = {0.f, 0.f, 0.f, 0.f};
#pragma unroll
    for (int kc = 0; kc < 8; ++kc) {
#pragma unroll
      for (int f = 0; f < 8; ++f) {
        half8 b = ldg8(qbase + ((size_t)(it * 8 + f) * 8 + kc) * 512 + lane * 8);
        s[f] = __builtin_amdgcn_mfma_f32_16x16x32_f16(kf[kc], b, s[f], 0, 0, 0);
      }
    }

    // softmax per j-row over 128 i (max-reduce in-loop; l accumulated lazily per-lane)
    float alpha[4];
#pragma unroll
    for (int r = 0; r < 4; ++r) {
      float mx = s[0][r];
#pragma unroll
      for (int f = 1; f < 8; ++f) mx = fmaxf(mx, s[f][r]);
#pragma unroll
      for (int off = 1; off < 16; off <<= 1) mx = fmaxf(mx, __shfl_xor(mx, off, 64));
      float mnew = fmaxf(m_run[r], mx);
      alpha[r] = __expf(m_run[r] - mnew);
      m_run[r] = mnew;
      float ps = 0.f;
#pragma unroll
      for (int f = 0; f < 8; ++f) {
        float pv = __expf(s[f][r] - mnew);
        ps += pv;
        sm.P[wave][f >> 1][quad * 4 + r][(f & 1) * 16 + row16] = (f16)pv;
      }
      l_lane[r] = l_lane[r] * alpha[r] + ps;
    }
#pragma unroll
    for (int ct = 0; ct < 16; ++ct)
#pragma unroll
      for (int r = 0; r < 4; ++r) O[ct][r] *= alpha[r];

    // PV: 4 chunks of 32 i; P same-wave LDS round-trip, packed vT frags
#pragma unroll
    for (int c4 = 0; c4 < 4; ++c4) {
      half8 pf = *reinterpret_cast<const half8*>(&sm.P[wave][c4][row16][quad * 8]);
      size_t vfb = ((size_t)(it * 4 + c4) * 16) * 512;
#pragma unroll
      for (int ct = 0; ct < 16; ++ct) {
        half8 vf = ldg8(vbase + vfb + (size_t)ct * 512 + lane * 8);
        O[ct] = __builtin_amdgcn_mfma_f32_16x16x32_f16(pf, vf, O[ct], 0, 0, 0);
      }
    }
  }

  // final l reduction (once) and normalization
  float inv[4];
#pragma unroll
  for (int r = 0; r < 4; ++r) {
    float l = l_lane[r];
#pragma unroll
    for (int off = 1; off < 16; off <<= 1) l += __shfl_xor(l, off, 64);
    inv[r] = 1.f / l;
  }

  // ---- phase B: MLP + LN on this wave's 16x256 att tile (per-wave LDS only) ----
#pragma unroll
  for (int ct = 0; ct < 16; ++ct)
#pragma unroll
    for (int r = 0; r < 4; ++r)
      sm.ex[wave][quad * 4 + r][ct * 16 + row16] = (f16)(O[ct][r] * inv[r]);

  half8 af[8];
#pragma unroll
  for (int kc = 0; kc < 8; ++kc)
    af[kc] = *reinterpret_cast<const half8*>(&sm.ex[wave][row16][kc * 32 + quad * 8]);

  // GEMM1: h = silu(att @ w1 + b1) -> ex (own-wave rows); packed weight frags
#pragma unroll
  for (int ct = 0; ct < 16; ++ct) {
    f32x4 acc = {0.f, 0.f, 0.f, 0.f};
    const f16* brow = w1p + ((size_t)ct * 8) * 512 + lane * 8;
#pragma unroll
    for (int kc = 0; kc < 8; ++kc)
      acc = __builtin_amdgcn_mfma_f32_16x16x32_f16(af[kc], ldg8(brow + kc * 512), acc, 0, 0, 0);
    int co = ct * 16 + row16;
    float bb = b1[co];
#pragma unroll
    for (int r = 0; r < 4; ++r) {
      float xg = acc[r] + bb;
      float hh = xg / (1.f + __expf(-xg));  // SiLU
      sm.ex[wave][quad * 4 + r][co] = (f16)hh;
    }
  }

  half8 hf[8];
#pragma unroll
  for (int kc = 0; kc < 8; ++kc)
    hf[kc] = *reinterpret_cast<const half8*>(&sm.ex[wave][row16][kc * 32 + quad * 8]);

  f32x4 acc2[16];
#pragma unroll
  for (int ct = 0; ct < 16; ++ct) {
    f32x4 acc = {0.f, 0.f, 0.f, 0.f};
    const f16* brow = w2p + ((size_t)ct * 8) * 512 + lane * 8;
#pragma unroll
    for (int kc = 0; kc < 8; ++kc)
      acc = __builtin_amdgcn_mfma_f32_16x16x32_f16(hf[kc], ldg8(brow + kc * 512), acc, 0, 0, 0);
    float bb = b2[ct * 16 + row16];
#pragma unroll
    for (int r = 0; r < 4; ++r) acc[r] += bb;
    acc2[ct] = acc;
  }

  // LayerNorm over C (per-row stats via 16-lane butterfly)
  float sum[4] = {0.f, 0.f, 0.f, 0.f}, ssq[4] = {0.f, 0.f, 0.f, 0.f};
#pragma unroll
  for (int ct = 0; ct < 16; ++ct)
#pragma unroll
    for (int r = 0; r < 4; ++r) { float xv = acc2[ct][r]; sum[r] += xv; ssq[r] += xv * xv; }
  float mean[4], rstd[4];
#pragma unroll
  for (int r = 0; r < 4; ++r) {
#pragma unroll
    for (int off = 1; off < 16; off <<= 1) {
      sum[r] += __shfl_xor(sum[r], off, 64);
      ssq[r] += __shfl_xor(ssq[r], off, 64);
    }
    mean[r] = sum[r] * (1.f / 256.f);
    float var = ssq[r] * (1.f / 256.f) - mean[r] * mean[r];
    rstd[r] = rsqrtf(var + 1e-5f);
  }

  // direct coalesced stores: out[bg][col][jw + quad*4 .. +3] = float4
#pragma unroll
  for (int ct = 0; ct < 16; ++ct) {
    int col = ct * 16 + row16;
    float g = gamma[col], be = beta[col];
    f32x4 v;
#pragma unroll
    for (int r = 0; r < 4; ++r) v[r] = (acc2[ct][r] - mean[r]) * rstd[r] * g + be;
    *reinterpret_cast<f32x4*>(out + (size_t)(bg * CC + col) * NN + jw + quad * 4) = v;
  }
}

extern "C" void kernel_launch(void* const* d_in, const int* in_sizes, int n_in,
                              void* d_out, int out_size, void* d_ws, size_t ws_size,
                              hipStream_t stream) {
  (void)in_sizes; (void)n_in; (void)out_size;
  const float* x     = (const float*)d_in[0];
  const float* wq    = (const float*)d_in[1];
  const float* bq    = (const float*)d_in[2];
  const float* wk    = (const float*)d_in[3];
  const float* bk    = (const float*)d_in[4];
  const float* wv    = (const float*)d_in[5];
  const float* bv    = (const float*)d_in[6];
  const float* w1    = (const float*)d_in[7];
  const float* b1    = (const float*)d_in[8];
  const float* w2    = (const float*)d_in[9];
  const float* b2    = (const float*)d_in[10];
  const float* gamma = (const float*)d_in[11];
  const float* beta  = (const float*)d_in[12];
  float* out = (float*)d_out;

  const size_t WE = 65536;
  const size_t SB = (size_t)NN * CC;
  f16* base = (f16*)d_ws;
  f16* wqp = base + 0 * WE;
  f16* wkp = base + 1 * WE;
  f16* wvp = base + 2 * WE;
  f16* w1p = base + 3 * WE;
  f16* w2p = base + 4 * WE;

  size_t wbytes = 5 * WE * sizeof(f16);
  size_t perb   = 3 * SB * sizeof(f16);
  int nb = (ws_size > wbytes) ? (int)((ws_size - wbytes) / perb) : 1;
  if (nb < 1) nb = 1;
  if (nb > BB) nb = BB;

  f16* qb  = base + 5 * WE;
  f16* kb  = qb + (size_t)nb * SB;
  f16* vTb = kb + (size_t)nb * SB;

  WP5 p;
  p.s[0] = wq; p.s[1] = wk; p.s[2] = wv; p.s[3] = w1; p.s[4] = w2;
  p.d[0] = wqp; p.d[1] = wkp; p.d[2] = wvp; p.d[3] = w1p; p.d[4] = w2p;
  k_packW<<<dim3(16, 5), 256, 0, stream>>>(p);

  for (int b0 = 0; b0 < BB; b0 += nb) {
    int cb = (b0 + nb <= BB) ? nb : (BB - b0);
    k_qkv<<<dim3(cb, 32, 3), 256, 0, stream>>>(x, wqp, wkp, wvp, bq, bk, bv, qb, kb, vTb, b0);
    k_attn_mlp<<<dim3(cb, 16), 256, 0, stream>>>(qb, kb, vTb, w1p, b1, w2p, b2,
                                                 gamma, beta, out, b0);
  }
}